// Round 9
// baseline (182.133 us; speedup 1.0000x reference)
//
#include <hip/hip_runtime.h>
#include <hip/hip_bf16.h>
#include <math.h>

#define B_SIZE 8192
#define D_SIZE 256
#define INV_T 14.285714285714286f
#define LOG2E 1.4426950408889634f
#define LN2 0.6931471805599453f
#define KEY_MASK 0xFFFFE000
#define COL_MASK 0x1FFF

typedef __bf16 bf16x8 __attribute__((ext_vector_type(8)));
typedef float f32x4 __attribute__((ext_vector_type(4)));

__device__ __forceinline__ void gload_lds16(const void* g, void* lds) {
  __builtin_amdgcn_global_load_lds(
      (const __attribute__((address_space(1))) void*)g,
      (__attribute__((address_space(3))) void*)lds, 16, 0, 0);
}

// int compare-exchange: a=max, b=min (v_max_i32 + v_min_i32)
__device__ __forceinline__ void cei(int& a, int& b) {
  const int h = a > b ? a : b;
  const int l = a > b ? b : a;
  a = h; b = l;
}

// merge two sorted-desc int-4 lists, keep top-4 in a
__device__ __forceinline__ void merge_top4i(int a[4], int b[4]) {
  cei(a[0], b[3]); cei(a[1], b[2]); cei(a[2], b[1]); cei(a[3], b[0]);
  cei(a[0], a[2]); cei(a[1], a[3]); cei(a[0], a[1]); cei(a[2], a[3]);
}

// ---------------------------------------------------------------------------
// K0: f32 -> bf16 for BOTH tensors; V side pre-scaled by INV_T*log2e.
// Blocks 0-15 also zero row_sum/col_sum.
// ---------------------------------------------------------------------------
__global__ __launch_bounds__(256) void cvt_both(
    const float* __restrict__ V, const float* __restrict__ T,
    __hip_bfloat16* __restrict__ Vb, __hip_bfloat16* __restrict__ Tb,
    float* __restrict__ sums) {
  const int b = blockIdx.x;
  if (b < 16)
    reinterpret_cast<float4*>(sums)[b * 256 + threadIdx.x] =
        float4{0.f, 0.f, 0.f, 0.f};
  const int half = b >> 11;                       // 0: V, 1: T
  const int i = (b & 2047) * 256 + threadIdx.x;   // 2048*256 = n4 per tensor
  const float sc = half ? 1.0f : (INV_T * LOG2E);
  const float* src = half ? T : V;
  __hip_bfloat16* dst = half ? Tb : Vb;
  const float4 v = reinterpret_cast<const float4*>(src)[i];
  union { __hip_bfloat16 h[4]; short4 s; } u;
  u.h[0] = __float2bfloat16(v.x * sc);
  u.h[1] = __float2bfloat16(v.y * sc);
  u.h[2] = __float2bfloat16(v.z * sc);
  u.h[3] = __float2bfloat16(v.w * sc);
  reinterpret_cast<short4*>(dst)[i] = u.s;
}

// ---------------------------------------------------------------------------
// K1: fused GEMM + register-side analysis, 8 waves (512 thr) on a 128x128
// tile. Wave (wr=wave>>1, wc=wave&1) computes a 32x64 output sub-tile:
// acc[2][4] = 32 AGPR (was 64) -> more waves/SIMD for latency hiding.
// Analysis identical to round-7 (packed int keys, exp2 domain).
// ---------------------------------------------------------------------------
__global__ __launch_bounds__(512) void gemm_analyze(
    const __hip_bfloat16* __restrict__ Vb, const __hip_bfloat16* __restrict__ Tb,
    float* __restrict__ row_sum, float* __restrict__ col_sum,
    float* __restrict__ diag, int* __restrict__ cand_key) {
  // As/Bs: 16 KB each. candK [128][17] ints (8704 B) aliases As afterwards.
  __shared__ __align__(16) char smem[32768];
  __shared__ float rsum[128];
  __shared__ float csum[128];

  const int tid  = threadIdx.x;
  const int wave = tid >> 6;         // 0..7
  const int lane = tid & 63;
  const int tileRow = blockIdx.x >> 6;
  const int tileCol = blockIdx.x & 63;
  const int wr = wave >> 1;          // 0..3  (32-row strip)
  const int wc = wave & 1;           // 0..1  (64-col half)
  const int g = lane >> 4;
  const int frow = lane & 15;
  const int rsw = frow & 7;          // read-side swizzle key

  __hip_bfloat16* As = reinterpret_cast<__hip_bfloat16*>(smem);  // [128][64]
  __hip_bfloat16* Bs = As + 128 * 64;

  if (tid < 128) rsum[tid] = 0.f;
  else if (tid < 256) csum[tid - 128] = 0.f;

  f32x4 acc[2][4];
#pragma unroll
  for (int m = 0; m < 2; ++m)
#pragma unroll
    for (int n = 0; n < 4; ++n)
      acc[m][n] = f32x4{0.f, 0.f, 0.f, 0.f};

  // staging: 512 threads cover 64 rows/issue; 2 issues per 128-row tile.
  // linear LDS dest + inverse-swizzled global source (rule 21).
  const int srow = tid >> 3;                          // 0..63 (+ i*64)
  const int scol = ((tid & 7) ^ ((tid >> 3) & 7)) * 8;
  const __hip_bfloat16* Ag = Vb + (size_t)(tileRow * 128 + srow) * D_SIZE + scol;
  const __hip_bfloat16* Bg = Tb + (size_t)(tileCol * 128 + srow) * D_SIZE + scol;
  char* AsW = (char*)As + wave * 1024;   // wave-uniform LDS dest base
  char* BsW = (char*)Bs + wave * 1024;

  for (int k0 = 0; k0 < D_SIZE; k0 += 64) {
#pragma unroll
    for (int i = 0; i < 2; ++i) {
      gload_lds16(Ag + (size_t)i * 64 * D_SIZE + k0, AsW + i * 8192);
      gload_lds16(Bg + (size_t)i * 64 * D_SIZE + k0, BsW + i * 8192);
    }
    __syncthreads();
#pragma unroll
    for (int ks = 0; ks < 64; ks += 32) {
      const int cbase = (ks >> 3) + g;
      const int coff = ((cbase ^ rsw) << 4);
      bf16x8 tf[4], vf[2];
#pragma unroll
      for (int n = 0; n < 4; ++n)
        tf[n] = *reinterpret_cast<const bf16x8*>(
            (const char*)Bs + (wc * 64 + n * 16 + frow) * 128 + coff);
#pragma unroll
      for (int m = 0; m < 2; ++m)
        vf[m] = *reinterpret_cast<const bf16x8*>(
            (const char*)As + (wr * 32 + m * 16 + frow) * 128 + coff);
#pragma unroll
      for (int m = 0; m < 2; ++m)
#pragma unroll
        for (int n = 0; n < 4; ++n)
          acc[m][n] = __builtin_amdgcn_mfma_f32_16x16x32_bf16(
              tf[n], vf[m], acc[m][n], 0, 0, 0);
    }
    __syncthreads();
  }

  // -------- register-side analysis (acc = sim/T * log2e) --------
  int* candK = reinterpret_cast<int*>(smem);    // [128][17]

  const bool diagT = (tileRow == tileCol);
  const int rowBase = tileRow * 128 + wr * 32;
  const int colOr = tileCol * 128 + wc * 64 + g * 4;  // low-13-bit index base

  float cp[16];
#pragma unroll
  for (int k = 0; k < 16; ++k) cp[k] = 0.f;

#pragma unroll
  for (int m = 0; m < 2; ++m) {
    float rs = 0.f;
    int t0 = (int)0x80000000, t1 = (int)0x80000000;
#pragma unroll
    for (int n = 0; n < 4; ++n) {
#pragma unroll
      for (int r = 0; r < 4; ++r) {
        const float a = acc[m][n][r];
        const float e = exp2f(a);
        rs += e;
        cp[n * 4 + r] += e;
        const int key =
            ((__float_as_int(a) & KEY_MASK) | colOr) | (n * 16 + r);
        t1 = max(t1, min(t0, key));
        t0 = max(t0, key);
      }
    }
    rs += __shfl_xor(rs, 16);
    rs += __shfl_xor(rs, 32);
    if (g == 0) atomicAdd(&rsum[wr * 32 + m * 16 + frow], rs);
    // diag sub-tile for this (wr,m): n index dn = wr*2 + m - wc*4 in [0,4)
    const int dn = wr * 2 + m - wc * 4;
    if (diagT && dn >= 0 && dn < 4 && g == (frow >> 2)) {
      const int rr = frow & 3;
      float dv = acc[m][dn][0];
      dv = rr == 1 ? acc[m][dn][1] : dv;
      dv = rr == 2 ? acc[m][dn][2] : dv;
      dv = rr == 3 ? acc[m][dn][3] : dv;
      diag[rowBase + m * 16 + frow] = dv * LN2;   // back to nats
      t0 = t1; t1 = (int)0x80000000;              // diag is lane max: drop it
    }
    const int cb = (wr * 32 + m * 16 + frow) * 17 + (wc * 4 + g) * 2;
    candK[cb] = t0; candK[cb + 1] = t1;
  }

  // col sums: transpose-reduce cp[16] across the 16-lane group
#pragma unroll
  for (int s = 8; s >= 1; s >>= 1) {
    const bool up = (lane & s) != 0;
#pragma unroll
    for (int k = 0; k < 8; ++k) {
      if (k < s) {
        const float send = up ? cp[k] : cp[k + s];
        const float recv = __shfl_xor(send, s);
        cp[k] = (up ? cp[k + s] : cp[k]) + recv;
      }
    }
  }
  atomicAdd(&csum[wc * 64 + ((frow >> 2) << 4) + (g << 2) + (frow & 3)], cp[0]);

  __syncthreads();

  // -------- per-row merge of 8 sorted-2 key lists + global writes --------
  if (tid < 128) {
    const int row = tid;
    const int base = row * 17;
    int a[4] = {candK[base], candK[base + 1], (int)0x80000000, (int)0x80000000};
#pragma unroll
    for (int l = 1; l < 8; ++l) {
      int b[4] = {candK[base + l * 2], candK[base + l * 2 + 1],
                  (int)0x80000000, (int)0x80000000};
      merge_top4i(a, b);
    }
    const int gRow = tileRow * 128 + row;
    const size_t cb = ((size_t)gRow << 8) + (tileCol << 2);
    int4 o; o.x = a[0]; o.y = a[1]; o.z = a[2]; o.w = a[3];
    *reinterpret_cast<int4*>(cand_key + cb) = o;
    atomicAdd(&row_sum[gRow], rsum[row]);
  } else if (tid < 256) {
    const int c = tid - 128;
    atomicAdd(&col_sum[tileCol * 128 + c], csum[c]);
  }
}

// ---------------------------------------------------------------------------
// K2: merge 64 per-tile sorted-4 key lists -> global top-4 per row; apply
// alpha corrections (2^{2a} - 2^a) to row_sum (owned) and col_sum (atomic).
// ---------------------------------------------------------------------------
__global__ __launch_bounds__(256) void merge_correct(
    const int* __restrict__ cand_key,
    float* __restrict__ row_sum, float* __restrict__ col_sum) {
  const int wave = threadIdx.x >> 6;
  const int lane = threadIdx.x & 63;
  const int row = blockIdx.x * 4 + wave;

  const int4 k4 = *reinterpret_cast<const int4*>(
      cand_key + ((size_t)row << 8) + lane * 4);
  int v[4] = {k4.x, k4.y, k4.z, k4.w};

#pragma unroll
  for (int s = 1; s < 64; s <<= 1) {
    int b[4];
#pragma unroll
    for (int k = 0; k < 4; ++k) b[k] = __shfl_xor(v[k], s);
    merge_top4i(v, b);
  }

  if (lane == 0) {
    float corr = 0.f;
#pragma unroll
    for (int k = 0; k < 4; ++k) {
      const float a = __int_as_float(v[k] & KEY_MASK);
      const float c = exp2f(a + a) - exp2f(a);
      corr += c;
      atomicAdd(&col_sum[v[k] & COL_MASK], c);
    }
    row_sum[row] += corr;   // exclusive owner after K1 completes
  }
}

// ---------------------------------------------------------------------------
// K3: final loss reduction
// ---------------------------------------------------------------------------
__global__ __launch_bounds__(256) void finalize(
    const float* __restrict__ row_sum, const float* __restrict__ col_sum,
    const float* __restrict__ diag, float* __restrict__ out) {
  double s = 0.0;
  for (int i = threadIdx.x; i < B_SIZE; i += 256)
    s += (double)(logf(row_sum[i]) + logf(col_sum[i]) - 2.f * diag[i]);
#pragma unroll
  for (int d = 1; d < 64; d <<= 1) s += __shfl_xor(s, d);
  __shared__ double red[4];
  const int lane = threadIdx.x & 63, wave = threadIdx.x >> 6;
  if (lane == 0) red[wave] = s;
  __syncthreads();
  if (threadIdx.x == 0) {
    const double tot = red[0] + red[1] + red[2] + red[3];
    out[0] = (float)(tot / (2.0 * (double)B_SIZE));
  }
}

// ---------------------------------------------------------------------------
extern "C" void kernel_launch(void* const* d_in, const int* in_sizes, int n_in,
                              void* d_out, int out_size, void* d_ws, size_t ws_size,
                              hipStream_t stream) {
  const float* V = (const float*)d_in[0];
  const float* T = (const float*)d_in[1];
  float* out = (float*)d_out;
  char* ws = (char*)d_ws;

  __hip_bfloat16* Vb = (__hip_bfloat16*)ws;                       // 4 MB
  __hip_bfloat16* Tb = (__hip_bfloat16*)(ws + (4 << 20));         // 4 MB
  float* row_sum = (float*)(ws + (8 << 20));                      // 32 KB
  float* col_sum = row_sum + B_SIZE;                              // 32 KB
  float* diag    = col_sum + B_SIZE;                              // 32 KB
  int*   cand_key = (int*)(ws + (8 << 20) + 3 * B_SIZE * 4);      // 8 MB

  cvt_both<<<4096, 256, 0, stream>>>(V, T, Vb, Tb, row_sum);
  gemm_analyze<<<64 * 64, 512, 0, stream>>>(Vb, Tb, row_sum, col_sum, diag,
                                            cand_key);
  merge_correct<<<B_SIZE / 4, 256, 0, stream>>>(cand_key, row_sum, col_sum);
  finalize<<<1, 256, 0, stream>>>(row_sum, col_sum, diag, out);
}